// Round 14
// baseline (134.441 us; speedup 1.0000x reference)
//
#include <hip/hip_runtime.h>
#include <math.h>

constexpr int B = 4;
constexpr int N = 8192;
constexpr int KNN = 8;
constexpr int NCELL = 4096;              // 16^3 Morton cells
constexpr int GSIZE = 16;                // points per group
constexpr int NGRP = N / GSIZE;          // 512 groups per cloud-batch
constexpr int QPB = 64;                  // queries per block (chamfer)
constexpr int WAVES = 8;                 // waves per chamfer block
constexpr int NCB = 2 * B;               // cloud-batches (0-3 pred, 4-7 tgt)

// Insert tv into sorted ascending d[0..7]. Exact: d'[0]=min(d0,tv),
// d'[i]=med3(d[i-1],d[i],tv). 8 independent ops. INF insert is a no-op.
__device__ __forceinline__ void insert8(float (&d)[KNN], float tv) {
  float n0 = fminf(d[0], tv);
  float n1 = __builtin_amdgcn_fmed3f(d[0], d[1], tv);
  float n2 = __builtin_amdgcn_fmed3f(d[1], d[2], tv);
  float n3 = __builtin_amdgcn_fmed3f(d[2], d[3], tv);
  float n4 = __builtin_amdgcn_fmed3f(d[3], d[4], tv);
  float n5 = __builtin_amdgcn_fmed3f(d[4], d[5], tv);
  float n6 = __builtin_amdgcn_fmed3f(d[5], d[6], tv);
  float n7 = __builtin_amdgcn_fmed3f(d[6], d[7], tv);
  d[0] = n0; d[1] = n1; d[2] = n2; d[3] = n3;
  d[4] = n4; d[5] = n5; d[6] = n6; d[7] = n7;
}

__device__ __forceinline__ int morton3(int x, int y, int z) {
  int m = 0;
#pragma unroll
  for (int b = 0; b < 4; ++b)
    m |= (((x >> b) & 1) << (3 * b + 2)) | (((y >> b) & 1) << (3 * b + 1)) |
         (((z >> b) & 1) << (3 * b + 0));
  return m;
}

__device__ __forceinline__ int point_cell(float x, float y, float z) {
  int cx = (int)fminf(fmaxf((x + 4.0f) * 2.0f, 0.0f), 15.0f);
  int cy = (int)fminf(fmaxf((y + 4.0f) * 2.0f, 0.0f), 15.0f);
  int cz = (int)fminf(fmaxf((z + 4.0f) * 2.0f, 0.0f), 15.0f);
  return morton3(cx, cy, cz);
}

// One block per cloud-batch (8 blocks x 1024 threads). LDS histogram ->
// in-block scan (global starts) -> scatter (points in registers) ->
// group AABBs. Verified structure (absmax 0 since round 4).
__global__ __launch_bounds__(1024) void prep_kernel(
    const float* __restrict__ src, const float* __restrict__ tgt,
    const float* __restrict__ flow, float4* __restrict__ pred_s,
    float4* __restrict__ tgt_s, int* __restrict__ starts,
    float4* __restrict__ gbox, float* __restrict__ out) {
  __shared__ int hist[NCELL];              // 16 KB: counts -> cursor
  __shared__ int wsum[16];
  int tid = threadIdx.x, cb = blockIdx.x;
  int cloud = cb >> 2, batch = cb & 3;
  if (cb == 0 && tid == 0) out[0] = 0.0f;

  for (int i = tid; i < NCELL; i += 1024) hist[i] = 0;
  __syncthreads();

  const float* __restrict__ bp = (cloud == 0 ? src : tgt) + batch * N * 3;
  const float* __restrict__ bf = flow + batch * N * 3;
  float4 pt[8];
  int cell[8];
#pragma unroll
  for (int k = 0; k < 8; ++k) {
    int i = k * 1024 + tid;
    float x = bp[3 * i + 0], y = bp[3 * i + 1], z = bp[3 * i + 2];
    if (cloud == 0) { x += bf[3 * i + 0]; y += bf[3 * i + 1]; z += bf[3 * i + 2]; }
    pt[k] = make_float4(x, y, z, 0.5f * (x * x + y * y + z * z));
    cell[k] = point_cell(x, y, z);
    atomicAdd(&hist[cell[k]], 1);
  }
  __syncthreads();

  int b4 = tid * 4;
  int h0v = hist[b4 + 0], h1v = hist[b4 + 1];
  int h2v = hist[b4 + 2], h3v = hist[b4 + 3];
  int s = h0v + h1v + h2v + h3v;
  int lane = tid & 63, w = tid >> 6;
  int incl = s;
#pragma unroll
  for (int off = 1; off < 64; off <<= 1) {
    int u = __shfl_up(incl, off, 64);
    if (lane >= off) incl += u;
  }
  if (lane == 63) wsum[w] = incl;
  __syncthreads();
  if (tid < 16) {
    int v = wsum[tid], inc = v;
#pragma unroll
    for (int off = 1; off < 16; off <<= 1) {
      int u = __shfl_up(inc, off, 64);
      if (tid >= off) inc += u;
    }
    wsum[tid] = inc - v;
  }
  __syncthreads();
  int run = incl - s + wsum[w];
  int* __restrict__ stg = starts + cb * (NCELL + 1);
  stg[b4 + 0] = run; hist[b4 + 0] = run; run += h0v;
  stg[b4 + 1] = run; hist[b4 + 1] = run; run += h1v;
  stg[b4 + 2] = run; hist[b4 + 2] = run; run += h2v;
  stg[b4 + 3] = run; hist[b4 + 3] = run; run += h3v;
  if (tid == 0) stg[NCELL] = N;
  __syncthreads();

  float4* __restrict__ dst = (cloud == 0 ? pred_s : tgt_s) + batch * N;
#pragma unroll
  for (int k = 0; k < 8; ++k) {
    int pos = atomicAdd(&hist[cell[k]], 1);
    dst[pos] = pt[k];
  }
  __threadfence_block();
  __syncthreads();

  if (tid < NGRP) {
    const float4* __restrict__ sp = dst + tid * GSIZE;
    float lx = INFINITY, ly = INFINITY, lz = INFINITY;
    float hx = -INFINITY, hy = -INFINITY, hz = -INFINITY;
#pragma unroll
    for (int t = 0; t < GSIZE; ++t) {
      float4 p = sp[t];
      lx = fminf(lx, p.x); ly = fminf(ly, p.y); lz = fminf(lz, p.z);
      hx = fmaxf(hx, p.x); hy = fmaxf(hy, p.y); hz = fmaxf(hz, p.z);
    }
    gbox[cb * 2 * NGRP + 2 * tid + 0] = make_float4(lx, ly, lz, 0.0f);
    gbox[cb * 2 * NGRP + 2 * tid + 1] = make_float4(hx, hy, hz, 0.0f);
  }
}

// Round-13 chamfer + ONE change: the cross-wave exchange now merges the full
// d-lists (true d8 of all 256 rank-matched seed candidates), not the min of
// per-wave thresholds. A residue subset at 1/8 density has d8 radius ~2x the
// true one (min over 8 subsets ~1.7x => ~5x ball volume) -- the merged d8 is
// ~1.0x, collapsing the passing-group count. Waves KEEP their own d-lists
// (adopting the merged list would duplicate candidates across waves and
// corrupt the final merge). Exactness: merged seed-d8 >= final merged d8,
// thr monotone non-increasing, box-min lower-bounds dist^2 => every skip
// justified (1e-5 margin covers fp rounding).
__global__ __launch_bounds__(512, 8) void chamfer_kernel(
    const float4* __restrict__ pred_s, const float4* __restrict__ tgt_s,
    const float4* __restrict__ aabb, float* __restrict__ out) {
  int blk = blockIdx.x;           // 1024 blocks
  int dir = blk >> 9;             // 0: pred->tgt, 1: tgt->pred
  int batch = (blk >> 7) & 3;
  int chunk = blk & 127;          // 128 chunks of 64 sorted queries
  const float4* __restrict__ qarr = (dir == 0 ? pred_s : tgt_s) + batch * N;
  const float4* __restrict__ parr = (dir == 0 ? tgt_s : pred_s) + batch * N;
  int ccb = (dir == 0 ? 4 + batch : batch);
  const float4* __restrict__ gb = aabb + ccb * (2 * NGRP);

  int lane = threadIdx.x & 63;
  int wv = __builtin_amdgcn_readfirstlane(threadIdx.x >> 6);

  __shared__ float4 boxes[2 * NGRP];            // 16 KB, shared by all waves
  __shared__ float part[WAVES][QPB][KNN + 1];   // 18 KB, exchange + merge

  for (int i = threadIdx.x; i < 2 * NGRP; i += 512) boxes[i] = gb[i];

  float4 q = qarr[chunk * QPB + lane];
  float nqx = -q.x, nqy = -q.y, nqz = -q.z;
  float two_qw = 2.0f * q.w;      // |q|^2

  float d[KNN];
#pragma unroll
  for (int i = 0; i < KNN; ++i) d[i] = INFINITY;
  float thr = INFINITY;

  __syncthreads();

  // Rank-matched start group index within this wave's residue class.
  int tc = (chunk * 4 + 6 - wv) >> 3;
  tc = max(0, min(63, tc));

  auto step = [&](int t) {
    int g = t * 8 + wv;                          // wave-uniform
    float4 lo = boxes[2 * g + 0];                // broadcast ds_read
    float4 hi = boxes[2 * g + 1];
    float dx = fmaxf(fmaxf(lo.x - q.x, q.x - hi.x), 0.0f);
    float dy = fmaxf(fmaxf(lo.y - q.y, q.y - hi.y), 0.0f);
    float dz = fmaxf(fmaxf(lo.z - q.z, q.z - hi.z), 0.0f);
    float md = __builtin_fmaf(dx, dx, __builtin_fmaf(dy, dy, dz * dz));
    if (__ballot(md < thr)) {
      const float4* __restrict__ gp = parr + g * GSIZE;  // uniform -> s_load
#pragma unroll
      for (int j = 0; j < GSIZE; ++j) {
        float4 p = gp[j];
        float tv = __builtin_fmaf(nqx, p.x, __builtin_fmaf(nqy, p.y,
                   __builtin_fmaf(nqz, p.z, p.w)));
        insert8(d, tv);
      }
      float cand = __builtin_fmaf(2.0f, d[KNN - 1], two_qw) * 1.00001f + 1e-6f;
      thr = fminf(thr, cand);
    }
  };

  // Phase A: 2 rank-matched groups per wave (16 per block, 256 pts/query).
  step(tc);
  if (tc + 1 < 64) step(tc + 1);

  // Cross-wave EXACT exchange: merge the 8 waves' d-lists (redundantly in
  // every wave, same query per lane) -> thr from the true seed d8.
#pragma unroll
  for (int i = 0; i < KNN; ++i) part[wv][lane][i] = d[i];
  __syncthreads();
  {
    float md[KNN];
#pragma unroll
    for (int i = 0; i < KNN; ++i) md[i] = part[0][lane][i];
    for (int s = 1; s < WAVES; ++s) {
#pragma unroll
      for (int i = 0; i < KNN; ++i) insert8(md, part[s][lane][i]);
    }
    float cand =
        __builtin_fmaf(2.0f, md[KNN - 1], two_qw) * 1.00001f + 1e-6f;
    thr = fminf(thr, cand);
  }
  __syncthreads();

  // Phase B: finish the zigzag with the near-true bound.
  for (int t = tc + 2; t < 64; ++t) step(t);
  for (int t = tc - 1; t >= 0; --t) step(t);

  // Merge 8 waves' sorted top-8 per query through LDS (stride 9).
#pragma unroll
  for (int i = 0; i < KNN; ++i) part[wv][lane][i] = d[i];
  __syncthreads();

  if (wv == 0) {
    float m[KNN];
#pragma unroll
    for (int i = 0; i < KNN; ++i) m[i] = part[0][lane][i];
    for (int s = 1; s < WAVES; ++s) {
#pragma unroll
      for (int i = 0; i < KNN; ++i) insert8(m, part[s][lane][i]);
    }
    float s_ = 0.0f;
#pragma unroll
    for (int i = 0; i < KNN; ++i) {
      float d2 = fmaxf(__builtin_fmaf(2.0f, m[i], two_qw), 0.0f);
      s_ += sqrtf(d2);
    }
    float val = s_ * (1.0f / KNN);
    for (int off = 32; off; off >>= 1) val += __shfl_down(val, off, 64);
    if (lane == 0) atomicAdd(out, val * (1.0f / (B * N)));
  }
}

extern "C" void kernel_launch(void* const* d_in, const int* in_sizes, int n_in,
                              void* d_out, int out_size, void* d_ws, size_t ws_size,
                              hipStream_t stream) {
  const float* src = (const float*)d_in[0];
  const float* tgt = (const float*)d_in[1];
  const float* flow = (const float*)d_in[2];
  float* out = (float*)d_out;

  float4* pred_s = (float4*)d_ws;                        // 512 KB
  float4* tgt_s = pred_s + B * N;                        // 512 KB
  float4* gbox = tgt_s + B * N;                          // 128 KB
  int* starts = (int*)(gbox + NCB * 2 * NGRP);           // 131 KB

  prep_kernel<<<NCB, 1024, 0, stream>>>(src, tgt, flow, pred_s, tgt_s, starts,
                                        gbox, out);
  chamfer_kernel<<<2 * B * (N / QPB), 512, 0, stream>>>(pred_s, tgt_s, gbox, out);
}

// Round 15
// 126.186 us; speedup vs baseline: 1.0654x; 1.0654x over previous
//
#include <hip/hip_runtime.h>
#include <math.h>

constexpr int B = 4;
constexpr int N = 8192;
constexpr int KNN = 8;
constexpr int NCELL = 4096;              // 16^3 Morton cells
constexpr int GSIZE = 16;                // points per group
constexpr int NGRP = N / GSIZE;          // 512 groups per cloud-batch
constexpr int QPB = 64;                  // queries per block (chamfer)
constexpr int WAVES = 8;                 // waves per chamfer block
constexpr int NCB = 2 * B;               // cloud-batches (0-3 pred, 4-7 tgt)

// Insert tv into sorted ascending d[0..7]. Exact: d'[0]=min(d0,tv),
// d'[i]=med3(d[i-1],d[i],tv). 8 independent ops. INF insert is a no-op.
__device__ __forceinline__ void insert8(float (&d)[KNN], float tv) {
  float n0 = fminf(d[0], tv);
  float n1 = __builtin_amdgcn_fmed3f(d[0], d[1], tv);
  float n2 = __builtin_amdgcn_fmed3f(d[1], d[2], tv);
  float n3 = __builtin_amdgcn_fmed3f(d[2], d[3], tv);
  float n4 = __builtin_amdgcn_fmed3f(d[3], d[4], tv);
  float n5 = __builtin_amdgcn_fmed3f(d[4], d[5], tv);
  float n6 = __builtin_amdgcn_fmed3f(d[5], d[6], tv);
  float n7 = __builtin_amdgcn_fmed3f(d[6], d[7], tv);
  d[0] = n0; d[1] = n1; d[2] = n2; d[3] = n3;
  d[4] = n4; d[5] = n5; d[6] = n6; d[7] = n7;
}

__device__ __forceinline__ int morton3(int x, int y, int z) {
  int m = 0;
#pragma unroll
  for (int b = 0; b < 4; ++b)
    m |= (((x >> b) & 1) << (3 * b + 2)) | (((y >> b) & 1) << (3 * b + 1)) |
         (((z >> b) & 1) << (3 * b + 0));
  return m;
}

__device__ __forceinline__ int point_cell(float x, float y, float z) {
  int cx = (int)fminf(fmaxf((x + 4.0f) * 2.0f, 0.0f), 15.0f);
  int cy = (int)fminf(fmaxf((y + 4.0f) * 2.0f, 0.0f), 15.0f);
  int cz = (int)fminf(fmaxf((z + 4.0f) * 2.0f, 0.0f), 15.0f);
  return morton3(cx, cy, cz);
}

// One block per cloud-batch (8 blocks x 1024 threads). LDS histogram ->
// in-block scan (cursor in LDS) -> scatter INTO LDS (random stores stay
// on-chip) -> coalesced global writeback -> AABBs from LDS (staggered reads).
// Same math as the verified version (absmax 0 since round 4); only the
// scatter/readback medium changed (global -> LDS). 144 KB LDS/block.
__global__ __launch_bounds__(1024) void prep_kernel(
    const float* __restrict__ src, const float* __restrict__ tgt,
    const float* __restrict__ flow, float4* __restrict__ pred_s,
    float4* __restrict__ tgt_s, float4* __restrict__ gbox,
    float* __restrict__ out) {
  __shared__ int hist[NCELL];              // 16 KB: counts -> cursor
  __shared__ int wsum[16];
  __shared__ float4 pts[N];                // 128 KB: sorted points
  int tid = threadIdx.x, cb = blockIdx.x;
  int cloud = cb >> 2, batch = cb & 3;
  if (cb == 0 && tid == 0) out[0] = 0.0f;

  for (int i = tid; i < NCELL; i += 1024) hist[i] = 0;
  __syncthreads();

  const float* __restrict__ bp = (cloud == 0 ? src : tgt) + batch * N * 3;
  const float* __restrict__ bf = flow + batch * N * 3;
  float4 pt[8];
  int cell[8];
#pragma unroll
  for (int k = 0; k < 8; ++k) {
    int i = k * 1024 + tid;
    float x = bp[3 * i + 0], y = bp[3 * i + 1], z = bp[3 * i + 2];
    if (cloud == 0) { x += bf[3 * i + 0]; y += bf[3 * i + 1]; z += bf[3 * i + 2]; }
    pt[k] = make_float4(x, y, z, 0.5f * (x * x + y * y + z * z));
    cell[k] = point_cell(x, y, z);
    atomicAdd(&hist[cell[k]], 1);
  }
  __syncthreads();

  // In-block exclusive scan of 4096 bins (4 per thread) -> cursor in hist.
  int b4 = tid * 4;
  int h0v = hist[b4 + 0], h1v = hist[b4 + 1];
  int h2v = hist[b4 + 2], h3v = hist[b4 + 3];
  int s = h0v + h1v + h2v + h3v;
  int lane = tid & 63, w = tid >> 6;
  int incl = s;
#pragma unroll
  for (int off = 1; off < 64; off <<= 1) {
    int u = __shfl_up(incl, off, 64);
    if (lane >= off) incl += u;
  }
  if (lane == 63) wsum[w] = incl;
  __syncthreads();
  if (tid < 16) {
    int v = wsum[tid], inc = v;
#pragma unroll
    for (int off = 1; off < 16; off <<= 1) {
      int u = __shfl_up(inc, off, 64);
      if (tid >= off) inc += u;
    }
    wsum[tid] = inc - v;
  }
  __syncthreads();
  int run = incl - s + wsum[w];
  hist[b4 + 0] = run; run += h0v;
  hist[b4 + 1] = run; run += h1v;
  hist[b4 + 2] = run; run += h2v;
  hist[b4 + 3] = run;
  __syncthreads();

  // Scatter into LDS (random stores stay on-chip).
#pragma unroll
  for (int k = 0; k < 8; ++k) {
    int pos = atomicAdd(&hist[cell[k]], 1);
    pts[pos] = pt[k];
  }
  __syncthreads();

  // Coalesced global writeback (chamfer reads this) + AABBs from LDS.
  float4* __restrict__ dst = (cloud == 0 ? pred_s : tgt_s) + batch * N;
#pragma unroll
  for (int k = 0; k < 8; ++k) dst[k * 1024 + tid] = pts[k * 1024 + tid];

  if (tid < NGRP) {
    float lx = INFINITY, ly = INFINITY, lz = INFINITY;
    float hx = -INFINITY, hy = -INFINITY, hz = -INFINITY;
#pragma unroll
    for (int t = 0; t < GSIZE; ++t) {
      int j = (t + tid) & 15;                // lane-stagger: cap bank conflicts
      float4 p = pts[tid * GSIZE + j];
      lx = fminf(lx, p.x); ly = fminf(ly, p.y); lz = fminf(lz, p.z);
      hx = fmaxf(hx, p.x); hy = fmaxf(hy, p.y); hz = fmaxf(hz, p.z);
    }
    gbox[cb * 2 * NGRP + 2 * tid + 0] = make_float4(lx, ly, lz, 0.0f);
    gbox[cb * 2 * NGRP + 2 * tid + 1] = make_float4(hx, hy, hz, 0.0f);
  }
}

// Round-13 chamfer, verbatim (measured 68.6 us, absmax 0): block = 8 waves x
// 64 lanes; lane = one sorted query; wave w owns residue class {g: g%8==w}.
// Zigzag from the rank-matched group vs the CURRENT per-lane threshold; after
// 2 groups/wave the 8 waves exchange thresholds through LDS (min over waves,
// same query per lane). Exactness: every wave's thr >= its subset's final d8
// >= merged final d8; cross-wave min preserves that bound; thr monotone
// non-increasing; box-min lower-bounds dist^2 => every skip justified
// (1e-5 margin covers fp rounding).
__global__ __launch_bounds__(512, 8) void chamfer_kernel(
    const float4* __restrict__ pred_s, const float4* __restrict__ tgt_s,
    const float4* __restrict__ aabb, float* __restrict__ out) {
  int blk = blockIdx.x;           // 1024 blocks
  int dir = blk >> 9;             // 0: pred->tgt, 1: tgt->pred
  int batch = (blk >> 7) & 3;
  int chunk = blk & 127;          // 128 chunks of 64 sorted queries
  const float4* __restrict__ qarr = (dir == 0 ? pred_s : tgt_s) + batch * N;
  const float4* __restrict__ parr = (dir == 0 ? tgt_s : pred_s) + batch * N;
  int ccb = (dir == 0 ? 4 + batch : batch);
  const float4* __restrict__ gb = aabb + ccb * (2 * NGRP);

  int lane = threadIdx.x & 63;
  int wv = __builtin_amdgcn_readfirstlane(threadIdx.x >> 6);

  __shared__ float4 boxes[2 * NGRP];            // 16 KB, shared by all waves
  __shared__ float part[WAVES][QPB][KNN + 1];   // 18 KB, exchange + merge

  for (int i = threadIdx.x; i < 2 * NGRP; i += 512) boxes[i] = gb[i];

  float4 q = qarr[chunk * QPB + lane];
  float nqx = -q.x, nqy = -q.y, nqz = -q.z;
  float two_qw = 2.0f * q.w;      // |q|^2

  float d[KNN];
#pragma unroll
  for (int i = 0; i < KNN; ++i) d[i] = INFINITY;
  float thr = INFINITY;

  __syncthreads();

  // Rank-matched start group index within this wave's residue class.
  int tc = (chunk * 4 + 6 - wv) >> 3;
  tc = max(0, min(63, tc));

  auto step = [&](int t) {
    int g = t * 8 + wv;                          // wave-uniform
    float4 lo = boxes[2 * g + 0];                // broadcast ds_read
    float4 hi = boxes[2 * g + 1];
    float dx = fmaxf(fmaxf(lo.x - q.x, q.x - hi.x), 0.0f);
    float dy = fmaxf(fmaxf(lo.y - q.y, q.y - hi.y), 0.0f);
    float dz = fmaxf(fmaxf(lo.z - q.z, q.z - hi.z), 0.0f);
    float md = __builtin_fmaf(dx, dx, __builtin_fmaf(dy, dy, dz * dz));
    if (__ballot(md < thr)) {
      const float4* __restrict__ gp = parr + g * GSIZE;  // uniform -> s_load
#pragma unroll
      for (int j = 0; j < GSIZE; ++j) {
        float4 p = gp[j];
        float tv = __builtin_fmaf(nqx, p.x, __builtin_fmaf(nqy, p.y,
                   __builtin_fmaf(nqz, p.z, p.w)));
        insert8(d, tv);
      }
      float cand = __builtin_fmaf(2.0f, d[KNN - 1], two_qw) * 1.00001f + 1e-6f;
      thr = fminf(thr, cand);
    }
  };

  // Phase A: 2 rank-matched groups per wave (16 per block, ~256 pts/query).
  step(tc);
  if (tc + 1 < 64) step(tc + 1);

  // Cross-wave threshold exchange: thr = min over the 8 waves (same query).
  part[wv][lane][0] = thr;
  __syncthreads();
  float tmin = part[0][lane][0];
#pragma unroll
  for (int s = 1; s < WAVES; ++s) tmin = fminf(tmin, part[s][lane][0]);
  thr = fminf(thr, tmin);
  __syncthreads();

  // Phase B: finish the zigzag with the combined (near-true) bound.
  for (int t = tc + 2; t < 64; ++t) step(t);
  for (int t = tc - 1; t >= 0; --t) step(t);

  // Merge 8 waves' sorted top-8 per query through LDS (stride 9).
#pragma unroll
  for (int i = 0; i < KNN; ++i) part[wv][lane][i] = d[i];
  __syncthreads();

  if (wv == 0) {
    float m[KNN];
#pragma unroll
    for (int i = 0; i < KNN; ++i) m[i] = part[0][lane][i];
    for (int s = 1; s < WAVES; ++s) {
#pragma unroll
      for (int i = 0; i < KNN; ++i) insert8(m, part[s][lane][i]);
    }
    float s_ = 0.0f;
#pragma unroll
    for (int i = 0; i < KNN; ++i) {
      float d2 = fmaxf(__builtin_fmaf(2.0f, m[i], two_qw), 0.0f);
      s_ += sqrtf(d2);
    }
    float val = s_ * (1.0f / KNN);
    for (int off = 32; off; off >>= 1) val += __shfl_down(val, off, 64);
    if (lane == 0) atomicAdd(out, val * (1.0f / (B * N)));
  }
}

extern "C" void kernel_launch(void* const* d_in, const int* in_sizes, int n_in,
                              void* d_out, int out_size, void* d_ws, size_t ws_size,
                              hipStream_t stream) {
  const float* src = (const float*)d_in[0];
  const float* tgt = (const float*)d_in[1];
  const float* flow = (const float*)d_in[2];
  float* out = (float*)d_out;

  float4* pred_s = (float4*)d_ws;                        // 512 KB
  float4* tgt_s = pred_s + B * N;                        // 512 KB
  float4* gbox = tgt_s + B * N;                          // 128 KB

  prep_kernel<<<NCB, 1024, 0, stream>>>(src, tgt, flow, pred_s, tgt_s, gbox,
                                        out);
  chamfer_kernel<<<2 * B * (N / QPB), 512, 0, stream>>>(pred_s, tgt_s, gbox, out);
}